// Round 12
// baseline (118.092 us; speedup 1.0000x reference)
//
#include <hip/hip_runtime.h>

#define NN 8192
#define DD 128
#define MAXCLS 64   // max members per class; Binom(8192,1/1024) mean 8 -> P(>64) negligible
#define NCHUNK 16   // j-chunks of 512 cols; GEMM grid = 16 x 64 = 1024 blocks = 4/CU, no tail
#define LOG2E 1.4426950408889634f
#define E1    2.718281828459045f   // e^margin, margin = 1

typedef __attribute__((ext_vector_type(8))) short bf16x8;
typedef __attribute__((ext_vector_type(4))) float f32x4;

#if __has_builtin(__builtin_amdgcn_exp2f)
#define EXP2F(x) __builtin_amdgcn_exp2f(x)
#else
#define EXP2F(x) exp2f(x)
#endif

// async global->LDS 16B: per-lane global address, LDS dest = wave-uniform base + lane*16
__device__ __forceinline__ void load16_lds(const unsigned short* g, unsigned short* l) {
    __builtin_amdgcn_global_load_lds(
        (const __attribute__((address_space(1))) unsigned int*)g,
        (__attribute__((address_space(3))) unsigned int*)l,
        16, 0, 0);
}

// ---------------- K0: fp32 -> bf16 (RNE) convert (pure; bucketing moved to K2) ----------------
__device__ __forceinline__ unsigned short f2bf(float x) {
    unsigned u = __float_as_uint(x);
    u = (u + 0x7FFFu + ((u >> 16) & 1u)) >> 16;
    return (unsigned short)u;
}

__global__ __launch_bounds__(256) void ml_convert_kernel(
    const float* __restrict__ a, const float* __restrict__ b,
    unsigned short* __restrict__ abf, unsigned short* __restrict__ bbf)
{
    int t = blockIdx.x * 256 + threadIdx.x;       // 0 .. 524287
    const float* src = a;
    unsigned short* dst = abf;
    int idx = t;
    float scale = LOG2E;                           // A rows carry the log2e factor
    if (t >= 262144) { src = b; dst = bbf; idx = t - 262144; scale = 1.0f; }
    float4 v = ((const float4*)src)[idx];
    ushort4 o;
    o.x = f2bf(v.x * scale); o.y = f2bf(v.y * scale);
    o.z = f2bf(v.z * scale); o.w = f2bf(v.w * scale);
    ((ushort4*)dst)[idx] = o;
}

// ---------------- K1: flash-style GEMM + unmasked exp2 row-sum -> Vp partials ----------------
// R12: no As LDS (A fragments direct from global, read once, register-resident);
// each wave owns a distinct 32-row band (no cross-wave combine). LDS = Bs dbuf only
// (32.5 KB) -> 4 blocks/CU with __launch_bounds__(256,4); grid (16,64)=1024 = 4/CU, no tail.
// B-staging total unchanged vs R6 (row-block count stays 64). B LDS swizzle: row r,
// 16B-chunk c at pos (c ^ (r&7)) -> DMA-linear AND conflict-free ds_read_b128.
__global__ __launch_bounds__(256, 4) void ml_vsum_gemm_kernel(
    const unsigned short* __restrict__ abf, const unsigned short* __restrict__ bbf,
    float* __restrict__ Vp)
{
    __shared__ unsigned short Bs[2][64 * DD];     // 2 x 16 KB
    const int tid  = threadIdx.x;
    const int lane = tid & 63;
    const int wv   = tid >> 6;
    const int row0 = blockIdx.y * 128;
    const int j0   = blockIdx.x * 512;

    const int lr = lane >> 4;      // staging: row-within-4
    const int sp = lane & 15;      // staging: slot
    const int m  = lane & 15;      // mfma row/col lane
    const int q  = lane >> 4;
    const int xr = m & 7;          // read-side swizzle key

    // ---- issue B tiles 0,1 into LDS ----
#pragma unroll
    for (int i = 0; i < 4; i++) {
        int rb = wv * 16 + i * 4;
        int r  = rb + lr;
        int cc = sp ^ (r & 7);
        load16_lds(&bbf[(size_t)(j0 + r) * DD + cc * 8], &Bs[0][rb * DD]);
    }
#pragma unroll
    for (int i = 0; i < 4; i++) {
        int rb = wv * 16 + i * 4;
        int r  = rb + lr;
        int cc = sp ^ (r & 7);
        load16_lds(&bbf[(size_t)(j0 + 64 + r) * DD + cc * 8], &Bs[1][rb * DD]);
    }

    // ---- A fragments direct from global (linear layout, no swizzle), read once ----
    // wave wv owns rows [row0 + wv*32, +32): ti<2 row-tiles of 16.
    const int wi = wv * 32;
    bf16x8 afr[2][4];
#pragma unroll
    for (int ti = 0; ti < 2; ti++)
#pragma unroll
        for (int ks = 0; ks < 4; ks++)
            afr[ti][ks] = *(const bf16x8*)(&abf[(size_t)(row0 + wi + ti * 16 + m) * DD + (ks * 4 + q) * 8]);

    float rs[2][4];
#pragma unroll
    for (int ti = 0; ti < 2; ti++)
#pragma unroll
        for (int rg = 0; rg < 4; rg++) rs[ti][rg] = 0.f;

    const f32x4 zero = {0.f, 0.f, 0.f, 0.f};
    __syncthreads();   // B tile 0 staged

    // ---- j-tile loop: 8 tiles of 64 cols, double-buffered ----
#pragma unroll 2
    for (int jt = 0; jt < 8; jt++) {
        const int pb = jt & 1;
        f32x4 acc[2][4];
#pragma unroll
        for (int ti = 0; ti < 2; ti++)
#pragma unroll
            for (int tj = 0; tj < 4; tj++) acc[ti][tj] = zero;

#pragma unroll
        for (int ks = 0; ks < 4; ks++) {
            bf16x8 bfr[4];
#pragma unroll
            for (int tj = 0; tj < 4; tj++) {
                int r   = tj * 16 + m;
                int pos = (ks * 4 + q) ^ xr;
                bfr[tj] = *(const bf16x8*)(&Bs[pb][r * DD + pos * 8]);
            }
#pragma unroll
            for (int ti = 0; ti < 2; ti++)
#pragma unroll
                for (int tj = 0; tj < 4; tj++)
                    acc[ti][tj] = __builtin_amdgcn_mfma_f32_16x16x32_bf16(afr[ti][ks], bfr[tj], acc[ti][tj], 0, 0, 0);
        }

        // epilogue: unmasked exp2 accumulate (A pre-scaled by log2e -> exp2(acc)=exp(S))
#pragma unroll
        for (int ti = 0; ti < 2; ti++)
#pragma unroll
            for (int tj = 0; tj < 4; tj++) {
                f32x4 c = acc[ti][tj];
                rs[ti][0] += EXP2F(c[0]);
                rs[ti][1] += EXP2F(c[1]);
                rs[ti][2] += EXP2F(c[2]);
                rs[ti][3] += EXP2F(c[3]);
            }

        __syncthreads();   // drains prefetch issued ~1 tile ago + all reads of buf[pb] done
        if (jt < 6) {
            int jb = j0 + (jt + 2) * 64;
#pragma unroll
            for (int i = 0; i < 4; i++) {
                int rb = wv * 16 + i * 4;
                int r  = rb + lr;
                int cc = sp ^ (r & 7);
                load16_lds(&bbf[(size_t)(jb + r) * DD + cc * 8], &Bs[pb][rb * DD]);
            }
        }
    }

    // ---- reduce over the 16 col-lanes, direct store (rows unique per wave) ----
#pragma unroll
    for (int ti = 0; ti < 2; ti++)
#pragma unroll
        for (int rg = 0; rg < 4; rg++) {
            float v = rs[ti][rg];
            v += __shfl_xor(v, 1);
            v += __shfl_xor(v, 2);
            v += __shfl_xor(v, 4);
            v += __shfl_xor(v, 8);
            rs[ti][rg] = v;
        }
    if (m == 0) {
#pragma unroll
        for (int ti = 0; ti < 2; ti++)
#pragma unroll
            for (int rg = 0; rg < 4; rg++)
                Vp[(size_t)blockIdx.x * NN + row0 + wi + ti * 16 + q * 4 + rg] = rs[ti][rg];
    }
}

// ---------------- K2: self-bucketing pairs: exact fp32 dots, V-adjust, hinge^2 ----------------
// R12: each block scans the 32 KB labels array for its own class members (8192 compares
// across 256 threads ~ free) -- removes the memset node, cnt/list arrays, and bucket
// atomics from K0. Plain slot stores; K3 reduces.
__global__ __launch_bounds__(256) void ml_pairs_kernel(
    const float* __restrict__ a, const float* __restrict__ b,
    const int* __restrict__ labels, const float* __restrict__ Vp,
    float* __restrict__ classLoss, int* __restrict__ classCnt)
{
    __shared__ int   mem[MAXCLS];
    __shared__ int   mcnt;
    __shared__ float sumExp[MAXCLS];
    __shared__ float Vadj[MAXCLS];
    __shared__ float Sc[MAXCLS * MAXCLS];   // 16 KB
    __shared__ float ps[4];
    __shared__ int   cs[4];

    const int c   = blockIdx.x;
    const int tid = threadIdx.x;

    if (tid == 0) mcnt = 0;
    if (tid < MAXCLS) sumExp[tid] = 0.f;
    __syncthreads();
    for (int j = tid; j < NN; j += 256) {
        if (labels[j] == c) {
            int p = atomicAdd(&mcnt, 1);       // LDS atomic
            if (p < MAXCLS) mem[p] = j;
        }
    }
    __syncthreads();
    int mc = mcnt;
    if (mc > MAXCLS) mc = MAXCLS;

    float vsum = 0.f;
    if (tid < mc) {
        int r = mem[tid];
#pragma unroll
        for (int jc = 0; jc < NCHUNK; jc++) vsum += Vp[(size_t)jc * NN + r];
    }
    __syncthreads();

    // ---- phase 1: mc^2 dots (16-lane groups), cache S, accumulate exp sums ----
    const int g = tid >> 4;                   // 16 groups
    const int l = tid & 15;
    const int tot1 = mc * mc;
    for (int pp = g; pp < tot1; pp += 16) {
        int i = pp / mc;
        int j = pp - i * mc;
        int ri = mem[i], rj = mem[j];
        const float4* ar = (const float4*)(a + (size_t)ri * DD) + l * 2;
        const float4* br = (const float4*)(b + (size_t)rj * DD) + l * 2;
        float4 a0 = ar[0], a1 = ar[1];
        float4 b0 = br[0], b1 = br[1];
        float s = 0.f;
        s = fmaf(a0.x, b0.x, s); s = fmaf(a0.y, b0.y, s);
        s = fmaf(a0.z, b0.z, s); s = fmaf(a0.w, b0.w, s);
        s = fmaf(a1.x, b1.x, s); s = fmaf(a1.y, b1.y, s);
        s = fmaf(a1.z, b1.z, s); s = fmaf(a1.w, b1.w, s);
        s += __shfl_xor(s, 1);
        s += __shfl_xor(s, 2);
        s += __shfl_xor(s, 4);
        s += __shfl_xor(s, 8);
        if (l == 0) {
            Sc[i * MAXCLS + j] = s;
            atomicAdd(&sumExp[i], __expf(s));   // LDS atomic, per-block
        }
    }
    __syncthreads();

    if (tid < mc) Vadj[tid] = E1 * (vsum - sumExp[tid]);
    __syncthreads();

    // ---- phase 2: one thread per ordered pair (i != j) ----
    float partial = 0.f;
    int   count   = 0;
    for (int pp = tid; pp < tot1; pp += 256) {
        int i = pp / mc;
        int j = pp - i * mc;
        if (i != j) {
            float h = fmaxf(logf(Vadj[i] + Vadj[j]) - Sc[i * MAXCLS + j], 0.f);
            partial += h * h;
            count++;
        }
    }
    for (int off = 32; off > 0; off >>= 1) {
        partial += __shfl_down(partial, off);
        count   += __shfl_down(count, off);
    }
    const int lane = tid & 63, wv = tid >> 6;
    if (lane == 0) { ps[wv] = partial; cs[wv] = count; }
    __syncthreads();
    if (tid == 0) {
        classLoss[c] = ps[0] + ps[1] + ps[2] + ps[3];   // plain stores (distinct addrs)
        classCnt[c]  = cs[0] + cs[1] + cs[2] + cs[3];
    }
}

// ---------------- K3: finalize (1 block) ----------------
__global__ __launch_bounds__(256) void ml_finalize_kernel(
    const float* __restrict__ classLoss, const int* __restrict__ classCnt,
    float* __restrict__ out)
{
    __shared__ double dred[4];
    __shared__ long long cred[4];
    const int tid = threadIdx.x;
    const int lane = tid & 63, wv = tid >> 6;

    double dls = 0.0;
    long long dct = 0;
    for (int k = tid; k < 1024; k += 256) {
        dls += (double)classLoss[k];
        dct += (long long)classCnt[k];
    }
    for (int off = 32; off > 0; off >>= 1) {
        dls += __shfl_down(dls, off);
        dct += __shfl_down(dct, off);
    }
    if (lane == 0) { dred[wv] = dls; cred[wv] = dct; }
    __syncthreads();
    if (tid == 0) {
        double ls = dred[0] + dred[1] + dred[2] + dred[3];
        long long np = cred[0] + cred[1] + cred[2] + cred[3];
        out[0] = (float)(ls / (2.0 * (double)np));
    }
}

// ---------------- launch ----------------
extern "C" void kernel_launch(void* const* d_in, const int* in_sizes, int n_in,
                              void* d_out, int out_size, void* d_ws, size_t ws_size,
                              hipStream_t stream)
{
    const float* a      = (const float*)d_in[0];
    const float* b      = (const float*)d_in[1];
    const int*   labels = (const int*)d_in[2];
    float* out = (float*)d_out;

    char* ws = (char*)d_ws;
    // ws layout (all regions written unconditionally; no zero-init needed):
    //   [0, 2MB)       a_bf16 (scaled by log2e)
    //   [2MB, 4MB)     b_bf16
    //   base2 = 4MB:
    //     +0        Vp[16*8192] f32     512 KB
    //     +524288   classLoss[1024]     4 KB
    //     +528384   classCnt[1024]      4 KB
    unsigned short* abf = (unsigned short*)ws;
    unsigned short* bbf = (unsigned short*)(ws + 2097152);
    char*  base2        = ws + 4194304;
    float* Vp           = (float*)(base2);
    float* classLoss    = (float*)(base2 + 524288);
    int*   classCnt     = (int*)(base2 + 528384);

    ml_convert_kernel<<<2048, 256, 0, stream>>>(a, b, abf, bbf);

    dim3 g(NCHUNK, NN / 128);
    ml_vsum_gemm_kernel<<<g, 256, 0, stream>>>(abf, bbf, Vp);

    ml_pairs_kernel<<<1024, 256, 0, stream>>>(a, b, labels, Vp, classLoss, classCnt);

    ml_finalize_kernel<<<1, 256, 0, stream>>>(classLoss, classCnt, out);
}

// Round 13
// 110.699 us; speedup vs baseline: 1.0668x; 1.0668x over previous
//
#include <hip/hip_runtime.h>

#define NN 8192
#define DD 128
#define MAXCLS 64   // max members per class; Binom(8192,1/1024) mean 8 -> P(>64) negligible
#define NCHUNK 8    // j-chunks; GEMM grid = NCHUNK x 64 = 512 blocks = 2/CU
#define LOG2E 1.4426950408889634f
#define E1    2.718281828459045f   // e^margin, margin = 1

typedef __attribute__((ext_vector_type(8))) short bf16x8;
typedef __attribute__((ext_vector_type(4))) float f32x4;

#if __has_builtin(__builtin_amdgcn_exp2f)
#define EXP2F(x) __builtin_amdgcn_exp2f(x)
#else
#define EXP2F(x) exp2f(x)
#endif

// async global->LDS 16B: per-lane global address, LDS dest = wave-uniform base + lane*16
__device__ __forceinline__ void load16_lds(const unsigned short* g, unsigned short* l) {
    __builtin_amdgcn_global_load_lds(
        (const __attribute__((address_space(1))) unsigned int*)g,
        (__attribute__((address_space(3))) unsigned int*)l,
        16, 0, 0);
}

// ---------------- K0: fp32 -> bf16 (RNE) convert (pure) ----------------
__device__ __forceinline__ unsigned short f2bf(float x) {
    unsigned u = __float_as_uint(x);
    u = (u + 0x7FFFu + ((u >> 16) & 1u)) >> 16;
    return (unsigned short)u;
}

__global__ __launch_bounds__(256) void ml_convert_kernel(
    const float* __restrict__ a, const float* __restrict__ b,
    unsigned short* __restrict__ abf, unsigned short* __restrict__ bbf)
{
    int t = blockIdx.x * 256 + threadIdx.x;       // 0 .. 524287
    const float* src = a;
    unsigned short* dst = abf;
    int idx = t;
    float scale = LOG2E;                           // A rows carry the log2e factor
    if (t >= 262144) { src = b; dst = bbf; idx = t - 262144; scale = 1.0f; }
    float4 v = ((const float4*)src)[idx];
    ushort4 o;
    o.x = f2bf(v.x * scale); o.y = f2bf(v.y * scale);
    o.z = f2bf(v.z * scale); o.w = f2bf(v.w * scale);
    ((ushort4*)dst)[idx] = o;
}

// ---------------- K1: flash-style GEMM + unmasked exp2 row-sum -> Vp partials ----------------
// EXACT R11/R6 structure (best measured; survived 4 attempts to beat it):
// 128-row blocks, grid (NCHUNK, 64) = 512 = 2/CU, A staged once via global_load_lds
// (fragments register-resident), 16 B-tiles of 64 cols double-buffered.
// LDS swizzle: row r, 16B-chunk c at pos (c ^ (r&7)) -> DMA-linear AND conflict-free b128.
__global__ __launch_bounds__(256, 2) void ml_vsum_gemm_kernel(
    const unsigned short* __restrict__ abf, const unsigned short* __restrict__ bbf,
    float* __restrict__ Vp)
{
    __shared__ unsigned short As[128 * DD];       // 32 KB
    __shared__ unsigned short Bs[2][64 * DD];     // 2 x 16 KB
    __shared__ float red[2][64];                  // cross-wave V combine

    const int tid  = threadIdx.x;
    const int lane = tid & 63;
    const int wv   = tid >> 6;
    const int row0 = blockIdx.y * 128;
    const int j0   = blockIdx.x * 1024;

    const int lr = lane >> 4;      // staging: row-within-4
    const int sp = lane & 15;      // staging: slot
    const int m  = lane & 15;      // mfma row/col lane
    const int q  = lane >> 4;
    const int xr = m & 7;          // read-side swizzle key

    // ---- issue A (once) + B tiles 0,1 ----
#pragma unroll
    for (int i = 0; i < 8; i++) {
        int rb = wv * 32 + i * 4;
        int r  = rb + lr;
        int cc = sp ^ (r & 7);
        load16_lds(&abf[(size_t)(row0 + r) * DD + cc * 8], &As[rb * DD]);
    }
#pragma unroll
    for (int i = 0; i < 4; i++) {
        int rb = wv * 16 + i * 4;
        int r  = rb + lr;
        int cc = sp ^ (r & 7);
        load16_lds(&bbf[(size_t)(j0 + r) * DD + cc * 8], &Bs[0][rb * DD]);
    }
#pragma unroll
    for (int i = 0; i < 4; i++) {
        int rb = wv * 16 + i * 4;
        int r  = rb + lr;
        int cc = sp ^ (r & 7);
        load16_lds(&bbf[(size_t)(j0 + 64 + r) * DD + cc * 8], &Bs[1][rb * DD]);
    }
    __syncthreads();

    const int wi = (wv >> 1) * 64;   // row-half
    const int wj = (wv & 1) * 32;    // col-half of the 64-col tile

    // ---- A fragments -> registers (read once) ----
    bf16x8 afr[4][4];
#pragma unroll
    for (int ti = 0; ti < 4; ti++)
#pragma unroll
        for (int ks = 0; ks < 4; ks++) {
            int r   = wi + ti * 16 + m;
            int pos = (ks * 4 + q) ^ xr;
            afr[ti][ks] = *(const bf16x8*)(&As[r * DD + pos * 8]);
        }

    float rs[4][4];
#pragma unroll
    for (int ti = 0; ti < 4; ti++)
#pragma unroll
        for (int rg = 0; rg < 4; rg++) rs[ti][rg] = 0.f;

    const f32x4 zero = {0.f, 0.f, 0.f, 0.f};

    // ---- j-tile loop: 16 tiles of 64 cols, double-buffered ----
#pragma unroll 2
    for (int jt = 0; jt < 16; jt++) {
        const int pb = jt & 1;
        f32x4 acc[4][2];
#pragma unroll
        for (int ti = 0; ti < 4; ti++)
#pragma unroll
            for (int tj = 0; tj < 2; tj++) acc[ti][tj] = zero;

#pragma unroll
        for (int ks = 0; ks < 4; ks++) {
            bf16x8 bfr[2];
#pragma unroll
            for (int tj = 0; tj < 2; tj++) {
                int r   = wj + tj * 16 + m;
                int pos = (ks * 4 + q) ^ xr;
                bfr[tj] = *(const bf16x8*)(&Bs[pb][r * DD + pos * 8]);
            }
#pragma unroll
            for (int ti = 0; ti < 4; ti++)
#pragma unroll
                for (int tj = 0; tj < 2; tj++)
                    acc[ti][tj] = __builtin_amdgcn_mfma_f32_16x16x32_bf16(afr[ti][ks], bfr[tj], acc[ti][tj], 0, 0, 0);
        }

        // epilogue: unmasked exp2 accumulate (A pre-scaled by log2e -> exp2(acc)=exp(S))
#pragma unroll
        for (int ti = 0; ti < 4; ti++)
#pragma unroll
            for (int tj = 0; tj < 2; tj++) {
                f32x4 c = acc[ti][tj];
                rs[ti][0] += EXP2F(c[0]);
                rs[ti][1] += EXP2F(c[1]);
                rs[ti][2] += EXP2F(c[2]);
                rs[ti][3] += EXP2F(c[3]);
            }

        __syncthreads();   // drains prefetch issued ~1 tile ago + all reads of buf[pb] done
        if (jt < 14) {
            int jb = j0 + (jt + 2) * 64;
#pragma unroll
            for (int i = 0; i < 4; i++) {
                int rb = wv * 16 + i * 4;
                int r  = rb + lr;
                int cc = sp ^ (r & 7);
                load16_lds(&bbf[(size_t)(jb + r) * DD + cc * 8], &Bs[pb][rb * DD]);
            }
        }
    }

    // ---- reduce over the 16 col-lanes ----
#pragma unroll
    for (int ti = 0; ti < 4; ti++)
#pragma unroll
        for (int rg = 0; rg < 4; rg++) {
            float v = rs[ti][rg];
            v += __shfl_xor(v, 1);
            v += __shfl_xor(v, 2);
            v += __shfl_xor(v, 4);
            v += __shfl_xor(v, 8);
            rs[ti][rg] = v;
        }

    // ---- cross-wave combine (col-half waves deposit; col-base waves add + store) ----
    if ((wv & 1) == 1 && m == 0) {
#pragma unroll
        for (int ti = 0; ti < 4; ti++)
#pragma unroll
            for (int rg = 0; rg < 4; rg++)
                red[wv >> 1][ti * 16 + q * 4 + rg] = rs[ti][rg];
    }
    __syncthreads();
    if ((wv & 1) == 0 && m == 0) {
#pragma unroll
        for (int ti = 0; ti < 4; ti++)
#pragma unroll
            for (int rg = 0; rg < 4; rg++) {
                int rloc = ti * 16 + q * 4 + rg;
                Vp[(size_t)blockIdx.x * NN + row0 + wi + rloc] = rs[ti][rg] + red[wv >> 1][rloc];
            }
    }
}

// ---------------- K2: self-bucketing pairs: exact fp32 dots, V-adjust, hinge^2 ----------------
// Each block scans the 32 KB labels array for its class members (32 loads/thread,
// L2-broadcast) -- removes the memset node, cnt/list arrays, and bucket atomics from K0.
// Plain slot stores (distinct addrs); K3 reduces. (Same-address device RMWs are the
// known pathology: R4 46us, R8 barrier 140us, R11 fix -14us.)
__global__ __launch_bounds__(256) void ml_pairs_kernel(
    const float* __restrict__ a, const float* __restrict__ b,
    const int* __restrict__ labels, const float* __restrict__ Vp,
    float* __restrict__ classLoss, int* __restrict__ classCnt)
{
    __shared__ int   mem[MAXCLS];
    __shared__ int   mcnt;
    __shared__ float sumExp[MAXCLS];
    __shared__ float Vadj[MAXCLS];
    __shared__ float Sc[MAXCLS * MAXCLS];   // 16 KB
    __shared__ float ps[4];
    __shared__ int   cs[4];

    const int c   = blockIdx.x;
    const int tid = threadIdx.x;

    if (tid == 0) mcnt = 0;
    if (tid < MAXCLS) sumExp[tid] = 0.f;
    __syncthreads();
    for (int j = tid; j < NN; j += 256) {
        if (labels[j] == c) {
            int p = atomicAdd(&mcnt, 1);       // LDS atomic
            if (p < MAXCLS) mem[p] = j;
        }
    }
    __syncthreads();
    int mc = mcnt;
    if (mc > MAXCLS) mc = MAXCLS;

    float vsum = 0.f;
    if (tid < mc) {
        int r = mem[tid];
#pragma unroll
        for (int jc = 0; jc < NCHUNK; jc++) vsum += Vp[(size_t)jc * NN + r];
    }
    __syncthreads();

    // ---- phase 1: mc^2 dots (16-lane groups), cache S, accumulate exp sums ----
    const int g = tid >> 4;                   // 16 groups
    const int l = tid & 15;
    const int tot1 = mc * mc;
    for (int pp = g; pp < tot1; pp += 16) {
        int i = pp / mc;
        int j = pp - i * mc;
        int ri = mem[i], rj = mem[j];
        const float4* ar = (const float4*)(a + (size_t)ri * DD) + l * 2;
        const float4* br = (const float4*)(b + (size_t)rj * DD) + l * 2;
        float4 a0 = ar[0], a1 = ar[1];
        float4 b0 = br[0], b1 = br[1];
        float s = 0.f;
        s = fmaf(a0.x, b0.x, s); s = fmaf(a0.y, b0.y, s);
        s = fmaf(a0.z, b0.z, s); s = fmaf(a0.w, b0.w, s);
        s = fmaf(a1.x, b1.x, s); s = fmaf(a1.y, b1.y, s);
        s = fmaf(a1.z, b1.z, s); s = fmaf(a1.w, b1.w, s);
        s += __shfl_xor(s, 1);
        s += __shfl_xor(s, 2);
        s += __shfl_xor(s, 4);
        s += __shfl_xor(s, 8);
        if (l == 0) {
            Sc[i * MAXCLS + j] = s;
            atomicAdd(&sumExp[i], __expf(s));   // LDS atomic, per-block
        }
    }
    __syncthreads();

    if (tid < mc) Vadj[tid] = E1 * (vsum - sumExp[tid]);
    __syncthreads();

    // ---- phase 2: one thread per ordered pair (i != j) ----
    float partial = 0.f;
    int   count   = 0;
    for (int pp = tid; pp < tot1; pp += 256) {
        int i = pp / mc;
        int j = pp - i * mc;
        if (i != j) {
            float h = fmaxf(logf(Vadj[i] + Vadj[j]) - Sc[i * MAXCLS + j], 0.f);
            partial += h * h;
            count++;
        }
    }
    for (int off = 32; off > 0; off >>= 1) {
        partial += __shfl_down(partial, off);
        count   += __shfl_down(count, off);
    }
    const int lane = tid & 63, wv = tid >> 6;
    if (lane == 0) { ps[wv] = partial; cs[wv] = count; }
    __syncthreads();
    if (tid == 0) {
        classLoss[c] = ps[0] + ps[1] + ps[2] + ps[3];   // plain stores (distinct addrs)
        classCnt[c]  = cs[0] + cs[1] + cs[2] + cs[3];
    }
}

// ---------------- K3: finalize (1 block) ----------------
__global__ __launch_bounds__(256) void ml_finalize_kernel(
    const float* __restrict__ classLoss, const int* __restrict__ classCnt,
    float* __restrict__ out)
{
    __shared__ double dred[4];
    __shared__ long long cred[4];
    const int tid = threadIdx.x;
    const int lane = tid & 63, wv = tid >> 6;

    double dls = 0.0;
    long long dct = 0;
    for (int k = tid; k < 1024; k += 256) {
        dls += (double)classLoss[k];
        dct += (long long)classCnt[k];
    }
    for (int off = 32; off > 0; off >>= 1) {
        dls += __shfl_down(dls, off);
        dct += __shfl_down(dct, off);
    }
    if (lane == 0) { dred[wv] = dls; cred[wv] = dct; }
    __syncthreads();
    if (tid == 0) {
        double ls = dred[0] + dred[1] + dred[2] + dred[3];
        long long np = cred[0] + cred[1] + cred[2] + cred[3];
        out[0] = (float)(ls / (2.0 * (double)np));
    }
}

// ---------------- launch ----------------
extern "C" void kernel_launch(void* const* d_in, const int* in_sizes, int n_in,
                              void* d_out, int out_size, void* d_ws, size_t ws_size,
                              hipStream_t stream)
{
    const float* a      = (const float*)d_in[0];
    const float* b      = (const float*)d_in[1];
    const int*   labels = (const int*)d_in[2];
    float* out = (float*)d_out;

    char* ws = (char*)d_ws;
    // ws layout (all regions written unconditionally; no zero-init needed):
    //   [0, 2MB)     a_bf16 (scaled by log2e)
    //   [2MB, 4MB)   b_bf16
    //   base2 = 4MB:
    //     +0        Vp[8*8192] f32      256 KB
    //     +262144   classLoss[1024]     4 KB
    //     +266240   classCnt[1024]      4 KB
    unsigned short* abf = (unsigned short*)ws;
    unsigned short* bbf = (unsigned short*)(ws + 2097152);
    char*  base2        = ws + 4194304;
    float* Vp           = (float*)(base2);
    float* classLoss    = (float*)(base2 + 262144);
    int*   classCnt     = (int*)(base2 + 266240);

    ml_convert_kernel<<<2048, 256, 0, stream>>>(a, b, abf, bbf);

    dim3 g(NCHUNK, NN / 128);
    ml_vsum_gemm_kernel<<<g, 256, 0, stream>>>(abf, bbf, Vp);

    ml_pairs_kernel<<<1024, 256, 0, stream>>>(a, b, labels, Vp, classLoss, classCnt);

    ml_finalize_kernel<<<1, 256, 0, stream>>>(classLoss, classCnt, out);
}

// Round 14
// 104.944 us; speedup vs baseline: 1.1253x; 1.0548x over previous
//
#include <hip/hip_runtime.h>

#define NN 8192
#define DD 128
#define MAXCLS 64   // max members per class; Binom(8192,1/1024) mean 8 -> P(>64) negligible
#define NCHUNK 8    // j-chunks; GEMM grid = NCHUNK x 64 = 512 blocks = 2/CU
#define LOG2E 1.4426950408889634f
#define E1    2.718281828459045f   // e^margin, margin = 1

typedef __attribute__((ext_vector_type(8))) short bf16x8;
typedef __attribute__((ext_vector_type(4))) float f32x4;

#if __has_builtin(__builtin_amdgcn_exp2f)
#define EXP2F(x) __builtin_amdgcn_exp2f(x)
#else
#define EXP2F(x) exp2f(x)
#endif

// async global->LDS 16B: per-lane global address, LDS dest = wave-uniform base + lane*16
__device__ __forceinline__ void load16_lds(const unsigned short* g, unsigned short* l) {
    __builtin_amdgcn_global_load_lds(
        (const __attribute__((address_space(1))) unsigned int*)g,
        (__attribute__((address_space(3))) unsigned int*)l,
        16, 0, 0);
}

// ---------------- K0: fp32 -> bf16 (RNE) convert + class bucketing ----------------
// Bucketing lives HERE (amortized into a running kernel): R13's per-block label scan
// in pairs cost +6.3us; this costs ~8 global atomics/class.
__device__ __forceinline__ unsigned short f2bf(float x) {
    unsigned u = __float_as_uint(x);
    u = (u + 0x7FFFu + ((u >> 16) & 1u)) >> 16;
    return (unsigned short)u;
}

__global__ __launch_bounds__(256) void ml_convert_kernel(
    const float* __restrict__ a, const float* __restrict__ b,
    const int* __restrict__ labels,
    unsigned short* __restrict__ abf, unsigned short* __restrict__ bbf,
    int* __restrict__ cnt, int* __restrict__ list)
{
    int t = blockIdx.x * 256 + threadIdx.x;       // 0 .. 524287
    const float* src = a;
    unsigned short* dst = abf;
    int idx = t;
    float scale = LOG2E;                           // A rows carry the log2e factor
    if (t >= 262144) { src = b; dst = bbf; idx = t - 262144; scale = 1.0f; }
    float4 v = ((const float4*)src)[idx];
    ushort4 o;
    o.x = f2bf(v.x * scale); o.y = f2bf(v.y * scale);
    o.z = f2bf(v.z * scale); o.w = f2bf(v.w * scale);
    ((ushort4*)dst)[idx] = o;

    if (t < NN) {   // fused bucket append (cnt pre-zeroed by memset; ~8 adds/address)
        int c = labels[t];
        int p = atomicAdd(&cnt[c], 1);
        if (p < MAXCLS) list[c * MAXCLS + p] = t;
    }
}

// ---------------- K1: flash-style GEMM + unmasked exp2 row-sum -> Vp partials ----------------
// Best-measured structure (survived 5 attempts to beat it: R8/R9 fusion, R10 row-split,
// R12 no-As occupancy, R13 — all regressed): 128-row blocks, grid (NCHUNK,64)=512=2/CU,
// A staged once via global_load_lds (fragments register-resident), 16 B-tiles of 64 cols
// double-buffered. LDS swizzle: row r, 16B-chunk c at pos (c ^ (r&7)) -> DMA-linear AND
// conflict-free ds_read_b128.
__global__ __launch_bounds__(256, 2) void ml_vsum_gemm_kernel(
    const unsigned short* __restrict__ abf, const unsigned short* __restrict__ bbf,
    float* __restrict__ Vp)
{
    __shared__ unsigned short As[128 * DD];       // 32 KB
    __shared__ unsigned short Bs[2][64 * DD];     // 2 x 16 KB
    __shared__ float red[2][64];                  // cross-wave V combine

    const int tid  = threadIdx.x;
    const int lane = tid & 63;
    const int wv   = tid >> 6;
    const int row0 = blockIdx.y * 128;
    const int j0   = blockIdx.x * 1024;

    const int lr = lane >> 4;      // staging: row-within-4
    const int sp = lane & 15;      // staging: slot
    const int m  = lane & 15;      // mfma row/col lane
    const int q  = lane >> 4;
    const int xr = m & 7;          // read-side swizzle key

    // ---- issue A (once) + B tiles 0,1 ----
#pragma unroll
    for (int i = 0; i < 8; i++) {
        int rb = wv * 32 + i * 4;
        int r  = rb + lr;
        int cc = sp ^ (r & 7);
        load16_lds(&abf[(size_t)(row0 + r) * DD + cc * 8], &As[rb * DD]);
    }
#pragma unroll
    for (int i = 0; i < 4; i++) {
        int rb = wv * 16 + i * 4;
        int r  = rb + lr;
        int cc = sp ^ (r & 7);
        load16_lds(&bbf[(size_t)(j0 + r) * DD + cc * 8], &Bs[0][rb * DD]);
    }
#pragma unroll
    for (int i = 0; i < 4; i++) {
        int rb = wv * 16 + i * 4;
        int r  = rb + lr;
        int cc = sp ^ (r & 7);
        load16_lds(&bbf[(size_t)(j0 + 64 + r) * DD + cc * 8], &Bs[1][rb * DD]);
    }
    __syncthreads();

    const int wi = (wv >> 1) * 64;   // row-half
    const int wj = (wv & 1) * 32;    // col-half of the 64-col tile

    // ---- A fragments -> registers (read once) ----
    bf16x8 afr[4][4];
#pragma unroll
    for (int ti = 0; ti < 4; ti++)
#pragma unroll
        for (int ks = 0; ks < 4; ks++) {
            int r   = wi + ti * 16 + m;
            int pos = (ks * 4 + q) ^ xr;
            afr[ti][ks] = *(const bf16x8*)(&As[r * DD + pos * 8]);
        }

    float rs[4][4];
#pragma unroll
    for (int ti = 0; ti < 4; ti++)
#pragma unroll
        for (int rg = 0; rg < 4; rg++) rs[ti][rg] = 0.f;

    const f32x4 zero = {0.f, 0.f, 0.f, 0.f};

    // ---- j-tile loop: 16 tiles of 64 cols, double-buffered ----
#pragma unroll 2
    for (int jt = 0; jt < 16; jt++) {
        const int pb = jt & 1;
        f32x4 acc[4][2];
#pragma unroll
        for (int ti = 0; ti < 4; ti++)
#pragma unroll
            for (int tj = 0; tj < 2; tj++) acc[ti][tj] = zero;

#pragma unroll
        for (int ks = 0; ks < 4; ks++) {
            bf16x8 bfr[2];
#pragma unroll
            for (int tj = 0; tj < 2; tj++) {
                int r   = wj + tj * 16 + m;
                int pos = (ks * 4 + q) ^ xr;
                bfr[tj] = *(const bf16x8*)(&Bs[pb][r * DD + pos * 8]);
            }
#pragma unroll
            for (int ti = 0; ti < 4; ti++)
#pragma unroll
                for (int tj = 0; tj < 2; tj++)
                    acc[ti][tj] = __builtin_amdgcn_mfma_f32_16x16x32_bf16(afr[ti][ks], bfr[tj], acc[ti][tj], 0, 0, 0);
        }

        // epilogue: unmasked exp2 accumulate (A pre-scaled by log2e -> exp2(acc)=exp(S))
#pragma unroll
        for (int ti = 0; ti < 4; ti++)
#pragma unroll
            for (int tj = 0; tj < 2; tj++) {
                f32x4 c = acc[ti][tj];
                rs[ti][0] += EXP2F(c[0]);
                rs[ti][1] += EXP2F(c[1]);
                rs[ti][2] += EXP2F(c[2]);
                rs[ti][3] += EXP2F(c[3]);
            }

        __syncthreads();   // drains prefetch issued ~1 tile ago + all reads of buf[pb] done
        if (jt < 14) {
            int jb = j0 + (jt + 2) * 64;
#pragma unroll
            for (int i = 0; i < 4; i++) {
                int rb = wv * 16 + i * 4;
                int r  = rb + lr;
                int cc = sp ^ (r & 7);
                load16_lds(&bbf[(size_t)(jb + r) * DD + cc * 8], &Bs[pb][rb * DD]);
            }
        }
    }

    // ---- reduce over the 16 col-lanes ----
#pragma unroll
    for (int ti = 0; ti < 4; ti++)
#pragma unroll
        for (int rg = 0; rg < 4; rg++) {
            float v = rs[ti][rg];
            v += __shfl_xor(v, 1);
            v += __shfl_xor(v, 2);
            v += __shfl_xor(v, 4);
            v += __shfl_xor(v, 8);
            rs[ti][rg] = v;
        }

    // ---- cross-wave combine (col-half waves deposit; col-base waves add + store) ----
    if ((wv & 1) == 1 && m == 0) {
#pragma unroll
        for (int ti = 0; ti < 4; ti++)
#pragma unroll
            for (int rg = 0; rg < 4; rg++)
                red[wv >> 1][ti * 16 + q * 4 + rg] = rs[ti][rg];
    }
    __syncthreads();
    if ((wv & 1) == 0 && m == 0) {
#pragma unroll
        for (int ti = 0; ti < 4; ti++)
#pragma unroll
            for (int rg = 0; rg < 4; rg++) {
                int rloc = ti * 16 + q * 4 + rg;
                Vp[(size_t)blockIdx.x * NN + row0 + wi + rloc] = rs[ti][rg] + red[wv >> 1][rloc];
            }
    }
}

// ---------------- K2: per-class exact fp32 dots, V-adjust, hinge^2 -> slot stores ----------------
// No done-counter / last-block reduce (same-address device RMWs are the measured
// pathology: R4 46us, R8 barrier ~140us, R11 fix -14us). Plain stores to per-class
// slots; kernel-boundary release makes them visible to K3.
__global__ __launch_bounds__(256) void ml_pairs_kernel(
    const float* __restrict__ a, const float* __restrict__ b,
    const int* __restrict__ cnt, const int* __restrict__ list,
    const float* __restrict__ Vp,
    float* __restrict__ classLoss, int* __restrict__ classCnt)
{
    __shared__ int   mem[MAXCLS];
    __shared__ float sumExp[MAXCLS];
    __shared__ float Vadj[MAXCLS];
    __shared__ float Sc[MAXCLS * MAXCLS];   // 16 KB
    __shared__ float ps[4];
    __shared__ int   cs[4];

    const int c   = blockIdx.x;
    const int tid = threadIdx.x;
    int mc = cnt[c];
    if (mc > MAXCLS) mc = MAXCLS;

    float vsum = 0.f;
    if (tid < mc) {
        int r = list[c * MAXCLS + tid];
        mem[tid] = r;
#pragma unroll
        for (int jc = 0; jc < NCHUNK; jc++) vsum += Vp[(size_t)jc * NN + r];
    }
    if (tid < MAXCLS) sumExp[tid] = 0.f;
    __syncthreads();

    // ---- phase 1: mc^2 dots (16-lane groups), cache S, accumulate exp sums ----
    const int g = tid >> 4;                   // 16 groups
    const int l = tid & 15;
    const int tot1 = mc * mc;
    for (int pp = g; pp < tot1; pp += 16) {
        int i = pp / mc;
        int j = pp - i * mc;
        int ri = mem[i], rj = mem[j];
        const float4* ar = (const float4*)(a + (size_t)ri * DD) + l * 2;
        const float4* br = (const float4*)(b + (size_t)rj * DD) + l * 2;
        float4 a0 = ar[0], a1 = ar[1];
        float4 b0 = br[0], b1 = br[1];
        float s = 0.f;
        s = fmaf(a0.x, b0.x, s); s = fmaf(a0.y, b0.y, s);
        s = fmaf(a0.z, b0.z, s); s = fmaf(a0.w, b0.w, s);
        s = fmaf(a1.x, b1.x, s); s = fmaf(a1.y, b1.y, s);
        s = fmaf(a1.z, b1.z, s); s = fmaf(a1.w, b1.w, s);
        s += __shfl_xor(s, 1);
        s += __shfl_xor(s, 2);
        s += __shfl_xor(s, 4);
        s += __shfl_xor(s, 8);
        if (l == 0) {
            Sc[i * MAXCLS + j] = s;
            atomicAdd(&sumExp[i], __expf(s));   // LDS atomic, per-block
        }
    }
    __syncthreads();

    if (tid < mc) Vadj[tid] = E1 * (vsum - sumExp[tid]);
    __syncthreads();

    // ---- phase 2: one thread per ordered pair (i != j) ----
    float partial = 0.f;
    int   count   = 0;
    for (int pp = tid; pp < tot1; pp += 256) {
        int i = pp / mc;
        int j = pp - i * mc;
        if (i != j) {
            float h = fmaxf(logf(Vadj[i] + Vadj[j]) - Sc[i * MAXCLS + j], 0.f);
            partial += h * h;
            count++;
        }
    }
    for (int off = 32; off > 0; off >>= 1) {
        partial += __shfl_down(partial, off);
        count   += __shfl_down(count, off);
    }
    const int lane = tid & 63, wv = tid >> 6;
    if (lane == 0) { ps[wv] = partial; cs[wv] = count; }
    __syncthreads();
    if (tid == 0) {
        classLoss[c] = ps[0] + ps[1] + ps[2] + ps[3];   // plain stores (distinct addrs)
        classCnt[c]  = cs[0] + cs[1] + cs[2] + cs[3];
    }
}

// ---------------- K3: finalize (1 block) ----------------
__global__ __launch_bounds__(256) void ml_finalize_kernel(
    const float* __restrict__ classLoss, const int* __restrict__ classCnt,
    float* __restrict__ out)
{
    __shared__ double dred[4];
    __shared__ long long cred[4];
    const int tid = threadIdx.x;
    const int lane = tid & 63, wv = tid >> 6;

    double dls = 0.0;
    long long dct = 0;
    for (int k = tid; k < 1024; k += 256) {
        dls += (double)classLoss[k];
        dct += (long long)classCnt[k];
    }
    for (int off = 32; off > 0; off >>= 1) {
        dls += __shfl_down(dls, off);
        dct += __shfl_down(dct, off);
    }
    if (lane == 0) { dred[wv] = dls; cred[wv] = dct; }
    __syncthreads();
    if (tid == 0) {
        double ls = dred[0] + dred[1] + dred[2] + dred[3];
        long long np = cred[0] + cred[1] + cred[2] + cred[3];
        out[0] = (float)(ls / (2.0 * (double)np));
    }
}

// ---------------- launch ----------------
extern "C" void kernel_launch(void* const* d_in, const int* in_sizes, int n_in,
                              void* d_out, int out_size, void* d_ws, size_t ws_size,
                              hipStream_t stream)
{
    const float* a      = (const float*)d_in[0];
    const float* b      = (const float*)d_in[1];
    const int*   labels = (const int*)d_in[2];
    float* out = (float*)d_out;

    char* ws = (char*)d_ws;
    // ws layout:
    //   [0, 2MB)   a_bf16 (scaled by log2e)    [2MB, 4MB)  b_bf16
    //   base2 = 4MB:
    //     +0       cnt[1024]            4096 B   (memset 0)
    //     +8192    classLoss[1024] f32  4096 B   (written unconditionally by K2)
    //     +12288   classCnt[1024] int   4096 B
    //     +16384   list[1024*64]        256 KB
    //     +278528  Vp[8*8192] f32       256 KB
    unsigned short* abf = (unsigned short*)ws;
    unsigned short* bbf = (unsigned short*)(ws + 2097152);
    char*     base2     = ws + 4194304;
    int*      cnt       = (int*)(base2);
    float*    classLoss = (float*)(base2 + 8192);
    int*      classCnt  = (int*)(base2 + 12288);
    int*      list      = (int*)(base2 + 16384);
    float*    Vp        = (float*)(base2 + 278528);

    (void)hipMemsetAsync(cnt, 0, 4096, stream);

    ml_convert_kernel<<<2048, 256, 0, stream>>>(a, b, labels, abf, bbf, cnt, list);

    dim3 g(NCHUNK, NN / 128);
    ml_vsum_gemm_kernel<<<g, 256, 0, stream>>>(abf, bbf, Vp);

    ml_pairs_kernel<<<1024, 256, 0, stream>>>(a, b, cnt, list, Vp, classLoss, classCnt);

    ml_finalize_kernel<<<1, 256, 0, stream>>>(classLoss, classCnt, out);
}